// Round 1
// baseline (887.660 us; speedup 1.0000x reference)
//
#include <hip/hip_runtime.h>

// Problem: out = x + 0.002 * einsum('bci,bij->bcj', f, softmax_i(einsum('bci,bcj->bij', f, f)))
// x: [8, 128, 64, 64] fp32.  b=8, c=d=128, n=wh=4096.
// == flash attention with Q=K=V=Ft (n x d), no scale, softmax over keys.
//
// ws layout: Ft bf16 [b][n][c] = 8*4096*128*2 = 8 MB (assumed <= ws_size).

typedef __bf16 bf16;
typedef bf16 bf16x8 __attribute__((ext_vector_type(8)));
typedef float f32x4 __attribute__((ext_vector_type(4)));

#define BATCH 8
#define CD 128
#define NN 4096
#define QBLK 64
#define KVB 32
#define KTS 136   // Kt row stride (bf16): 272 B, 16B-aligned, 2-way banks
#define VTS 40    // Vt/P row stride (bf16): 80 B, 16B-aligned, 2-way banks

// ---------------- kernel 1: x [b][c][n] f32 -> Ft [b][n][c] bf16 ----------------
__global__ __launch_bounds__(256) void transpose_to_bf16(const float* __restrict__ x,
                                                         bf16* __restrict__ ft) {
    __shared__ float tile[32][33];
    const int n0 = blockIdx.x * 32;
    const int c0 = blockIdx.y * 32;
    const int b  = blockIdx.z;
    const int tx = threadIdx.x, ty = threadIdx.y;

    const float* xp = x + ((size_t)b * CD + c0) * NN + n0;
#pragma unroll
    for (int r = 0; r < 4; r++)
        tile[ty + r * 8][tx] = xp[(size_t)(ty + r * 8) * NN + tx];
    __syncthreads();
    bf16* fp = ft + ((size_t)b * NN + n0) * CD + c0;
#pragma unroll
    for (int r = 0; r < 4; r++)
        fp[(size_t)(ty + r * 8) * CD + tx] = (bf16)tile[tx][ty + r * 8];
}

// ---------------- kernel 2: flash attention + fused residual ----------------
// grid = 8 batches * 64 q-tiles = 512 blocks, 256 threads (4 waves).
// wave w owns 16 q rows: q0 + w*16 .. +16.  KV loop in steps of 32 keys.
__global__ __launch_bounds__(256) void attn_kernel(const float* __restrict__ x,
                                                   const bf16* __restrict__ ft,
                                                   float* __restrict__ out) {
    const int tid = threadIdx.x;
    const int w   = tid >> 6;
    const int l   = tid & 63;
    const int l15 = l & 15;
    const int l4  = l >> 4;

    const int batch = blockIdx.x >> 6;
    const int qt    = blockIdx.x & 63;
    const int q0    = qt * QBLK;

    const bf16* ftb = ft + (size_t)batch * NN * CD;

    __shared__ union {
        struct {
            bf16 kt[KVB][KTS];    // [key][c]
            bf16 vt[CD][VTS];     // [c][key]  (transposed for PV B-frags)
            bf16 p[4][16][VTS];   // per-wave P tile [q][key]
        } s;
        float o[QBLK][CD + 4];    // epilogue O tile [q][c]
    } sm;

    // Q fragments: A[m=q][k=c]; lane holds row l&15, k = (l>>4)*8+e
    bf16x8 qf[4];
    {
        const bf16* qrow = ftb + (size_t)(q0 + w * 16 + l15) * CD + l4 * 8;
#pragma unroll
        for (int ct = 0; ct < 4; ct++)
            qf[ct] = *reinterpret_cast<const bf16x8*>(qrow + ct * 32);
    }

    const f32x4 zero = {0.0f, 0.0f, 0.0f, 0.0f};
    f32x4 oacc[8];
#pragma unroll
    for (int i = 0; i < 8; i++) oacc[i] = zero;
    float m_run[4], l_run[4];
#pragma unroll
    for (int r = 0; r < 4; r++) { m_run[r] = -1e30f; l_run[r] = 0.0f; }

    for (int i0 = 0; i0 < NN; i0 += KVB) {
        __syncthreads();                     // previous tile fully consumed
        // stage K/V tile: Kt[key][c] and Vt[c][key]
        for (int idx = tid; idx < KVB * CD; idx += 256) {
            const int ki = idx >> 7;         // 0..31
            const int c  = idx & 127;
            const bf16 v = ftb[(size_t)(i0 + ki) * CD + c];
            sm.s.kt[ki][c] = v;
            sm.s.vt[c][ki] = v;
        }
        __syncthreads();

        // S[q][key] = sum_c Q[q][c] * K[key][c]
        f32x4 s[2];
#pragma unroll
        for (int g = 0; g < 2; g++) {
            s[g] = zero;
#pragma unroll
            for (int ct = 0; ct < 4; ct++) {
                bf16x8 kf = *reinterpret_cast<const bf16x8*>(
                    &sm.s.kt[g * 16 + l15][ct * 32 + l4 * 8]);
                s[g] = __builtin_amdgcn_mfma_f32_16x16x32_bf16(qf[ct], kf, s[g], 0, 0, 0);
            }
        }

        // online softmax over keys (D-layout: col=key=lane&15, row=q=(lane>>4)*4+r)
        float mp[4], sum[4], pexp[2][4], alpha[4];
#pragma unroll
        for (int r = 0; r < 4; r++) mp[r] = fmaxf(s[0][r], s[1][r]);
#pragma unroll
        for (int off = 8; off >= 1; off >>= 1)
#pragma unroll
            for (int r = 0; r < 4; r++)
                mp[r] = fmaxf(mp[r], __shfl_xor(mp[r], off));
#pragma unroll
        for (int r = 0; r < 4; r++) {
            const float mn = fmaxf(m_run[r], mp[r]);
            alpha[r]   = __expf(m_run[r] - mn);
            m_run[r]   = mn;
            pexp[0][r] = __expf(s[0][r] - mn);
            pexp[1][r] = __expf(s[1][r] - mn);
            sum[r]     = pexp[0][r] + pexp[1][r];
        }
#pragma unroll
        for (int off = 8; off >= 1; off >>= 1)
#pragma unroll
            for (int r = 0; r < 4; r++)
                sum[r] += __shfl_xor(sum[r], off);
#pragma unroll
        for (int r = 0; r < 4; r++)
            l_run[r] = l_run[r] * alpha[r] + sum[r];

        // rescale O
#pragma unroll
        for (int ct = 0; ct < 8; ct++)
#pragma unroll
            for (int r = 0; r < 4; r++)
                oacc[ct][r] *= alpha[r];

        // P (C-layout) -> LDS -> A-layout (wave-local; in-order DS pipe, no barrier)
#pragma unroll
        for (int g = 0; g < 2; g++)
#pragma unroll
            for (int r = 0; r < 4; r++)
                sm.s.p[w][l4 * 4 + r][g * 16 + l15] = (bf16)pexp[g][r];

        bf16x8 pf = *reinterpret_cast<const bf16x8*>(&sm.s.p[w][l15][l4 * 8]);
#pragma unroll
        for (int ct = 0; ct < 8; ct++) {
            bf16x8 vf = *reinterpret_cast<const bf16x8*>(
                &sm.s.vt[ct * 16 + l15][l4 * 8]);
            oacc[ct] = __builtin_amdgcn_mfma_f32_16x16x32_bf16(pf, vf, oacc[ct], 0, 0, 0);
        }
    }

    __syncthreads();   // all waves done with s-union before o-union reuse
    // O to LDS (normalize by l), then fused residual write
#pragma unroll
    for (int r = 0; r < 4; r++) {
        const float rl = 1.0f / l_run[r];
#pragma unroll
        for (int ct = 0; ct < 8; ct++)
            sm.o[w * 16 + l4 * 4 + r][ct * 16 + l15] = oacc[ct][r] * rl;
    }
    __syncthreads();

    const size_t xbase = (size_t)batch * CD * NN;
    for (int idx = tid; idx < QBLK * CD; idx += 256) {
        const int c = idx >> 6;
        const int q = idx & 63;
        const size_t g = xbase + (size_t)c * NN + q0 + q;
        out[g] = x[g] + 0.002f * sm.o[q][c];
    }
}

extern "C" void kernel_launch(void* const* d_in, const int* in_sizes, int n_in,
                              void* d_out, int out_size, void* d_ws, size_t ws_size,
                              hipStream_t stream) {
    const float* x = (const float*)d_in[0];
    float* out = (float*)d_out;
    bf16* ft = (bf16*)d_ws;   // 8 MB

    dim3 tb1(32, 8);
    dim3 tg1(NN / 32, CD / 32, BATCH);
    transpose_to_bf16<<<tg1, tb1, 0, stream>>>(x, ft);

    attn_kernel<<<512, 256, 0, stream>>>(x, ft, out);
}

// Round 2
// 300.554 us; speedup vs baseline: 2.9534x; 2.9534x over previous
//
#include <hip/hip_runtime.h>

// out = x + 0.002 * einsum('bci,bij->bcj', f, softmax_i(einsum('bci,bcj->bij', f, f)))
// x: [8, 128, 64, 64] fp32.  b=8, c=d=128, n=wh=4096.
// Flash attention, Q=K=V=Ft (n x d), softmax over keys.
// ws: Ft bf16 [b][n][c] = 8 MB.

typedef __bf16 bf16;
typedef bf16 bf16x4 __attribute__((ext_vector_type(4)));
typedef bf16 bf16x8 __attribute__((ext_vector_type(8)));
typedef float f32x4 __attribute__((ext_vector_type(4)));

#define BATCH 8
#define CD 128
#define NN 4096
#define QBLK 64
#define KVB 64
#define NT (NN / KVB)
#define KTS 132   // kt row stride (bf16): 264 B -> bank offset 2/row, even spread
#define VTS 68    // vt row stride (bf16): 136 B -> bank offset 2/row
#define PTS 80    // p row stride  (bf16): 160 B -> bank offset 8/row

// ---------------- kernel 1: x [b][c][n] f32 -> Ft [b][n][c] bf16 ----------------
__global__ __launch_bounds__(256) void transpose_to_bf16(const float* __restrict__ x,
                                                         bf16* __restrict__ ft) {
    __shared__ float tile[32][33];
    const int n0 = blockIdx.x * 32;
    const int c0 = blockIdx.y * 32;
    const int b  = blockIdx.z;
    const int tx = threadIdx.x, ty = threadIdx.y;

    const float* xp = x + ((size_t)b * CD + c0) * NN + n0;
#pragma unroll
    for (int r = 0; r < 4; r++)
        tile[ty + r * 8][tx] = xp[(size_t)(ty + r * 8) * NN + tx];
    __syncthreads();
    bf16* fp = ft + ((size_t)b * NN + n0) * CD + c0;
#pragma unroll
    for (int r = 0; r < 4; r++)
        fp[(size_t)(ty + r * 8) * CD + tx] = (bf16)tile[tx][ty + r * 8];
}

// ---------------- kernel 2: flash attention + fused residual ----------------
// 512 blocks (8 batch x 64 q-tiles), 256 threads (4 waves, 16 q-rows each).
// KV loop: 64 keys/iter, double-buffered LDS, 1 barrier/iter.
__global__ __launch_bounds__(256, 2) void attn_kernel(const float* __restrict__ x,
                                                      const bf16* __restrict__ ft,
                                                      float* __restrict__ out) {
    const int tid = threadIdx.x;
    const int w   = tid >> 6;
    const int l   = tid & 63;
    const int l15 = l & 15;
    const int l4  = l >> 4;

    const int batch = blockIdx.x >> 6;
    const int q0    = (blockIdx.x & 63) * QBLK;

    const bf16*  ftb = ft + (size_t)batch * NN * CD;
    const float* xb  = x  + (size_t)batch * CD * NN;

    __shared__ union {
        struct {
            bf16 kt[2][KVB][KTS];   // [key][c]       33792 B
            bf16 vt[2][CD][VTS];    // [c][key]       34816 B  (== x layout, no transpose!)
            bf16 p[4][16][PTS];     // per-wave P     10240 B
        } s;
        float o[QBLK][CD + 4];      // epilogue       33792 B
    } sm;

    // Q fragments: A[m=q][k=c]; lane holds row l&15, k=(l>>4)*8+e
    bf16x8 qf[4];
    {
        const bf16* qrow = ftb + (size_t)(q0 + w * 16 + l15) * CD + l4 * 8;
#pragma unroll
        for (int ct = 0; ct < 4; ct++)
            qf[ct] = *reinterpret_cast<const bf16x8*>(qrow + ct * 32);
    }

    // staging geometry: 16 lanes per row-chunk
    const int srow = tid >> 4;   // 0..15
    const int sch  = tid & 15;   // 0..15

    bf16x8 kreg[4];
    f32x4  vreg[8];

    auto stage_load = [&](int i0) {
#pragma unroll
        for (int j = 0; j < 4; j++)   // kt: 64 rows x 256B, bf16x8/lane
            kreg[j] = *reinterpret_cast<const bf16x8*>(
                ftb + (size_t)(i0 + j * 16 + srow) * CD + sch * 8);
#pragma unroll
        for (int j = 0; j < 8; j++)   // vt: 128 rows x 256B of x, float4/lane
            vreg[j] = *reinterpret_cast<const f32x4*>(
                xb + (size_t)(j * 16 + srow) * NN + i0 + sch * 4);
    };
    auto stage_write = [&](int buf) {
#pragma unroll
        for (int j = 0; j < 4; j++)
            *reinterpret_cast<bf16x8*>(&sm.s.kt[buf][j * 16 + srow][sch * 8]) = kreg[j];
#pragma unroll
        for (int j = 0; j < 8; j++) {
            bf16x4 t;
#pragma unroll
            for (int e = 0; e < 4; e++) t[e] = (bf16)vreg[j][e];
            *reinterpret_cast<bf16x4*>(&sm.s.vt[buf][j * 16 + srow][sch * 4]) = t;
        }
    };

    const f32x4 zero = {0.0f, 0.0f, 0.0f, 0.0f};
    f32x4 oacc[8];
#pragma unroll
    for (int i = 0; i < 8; i++) oacc[i] = zero;
    float m_run[4], l_run[4];
#pragma unroll
    for (int r = 0; r < 4; r++) { m_run[r] = -1e30f; l_run[r] = 0.0f; }

    stage_load(0);
    stage_write(0);
    __syncthreads();

    for (int it = 0; it < NT; ++it) {
        const int cur = it & 1;
        if (it + 1 < NT) stage_load((it + 1) * KVB);   // in flight during compute

        // ---- QK^T: S[q][key], 16 MFMA ----
        f32x4 s[4];
        __builtin_amdgcn_s_setprio(1);
#pragma unroll
        for (int g = 0; g < 4; g++) {
            s[g] = zero;
#pragma unroll
            for (int ct = 0; ct < 4; ct++) {
                bf16x8 kf = *reinterpret_cast<const bf16x8*>(
                    &sm.s.kt[cur][g * 16 + l15][ct * 32 + l4 * 8]);
                s[g] = __builtin_amdgcn_mfma_f32_16x16x32_bf16(qf[ct], kf, s[g], 0, 0, 0);
            }
        }
        __builtin_amdgcn_s_setprio(0);

        // ---- online softmax over keys (D-layout: col=key=l&15, row=q=(l>>4)*4+r) ----
        float mp[4];
#pragma unroll
        for (int r = 0; r < 4; r++)
            mp[r] = fmaxf(fmaxf(s[0][r], s[1][r]), fmaxf(s[2][r], s[3][r]));
#pragma unroll
        for (int off = 8; off >= 1; off >>= 1)
#pragma unroll
            for (int r = 0; r < 4; r++)
                mp[r] = fmaxf(mp[r], __shfl_xor(mp[r], off));

        bool need = false;
#pragma unroll
        for (int r = 0; r < 4; r++) need = need || (mp[r] > m_run[r] + 8.0f);
        if (__any(need)) {   // defer-max: rescale only when max grew past threshold
#pragma unroll
            for (int r = 0; r < 4; r++) {
                const float mn    = fmaxf(m_run[r], mp[r]);
                const float alpha = __expf(m_run[r] - mn);
                m_run[r] = mn;
                l_run[r] *= alpha;
#pragma unroll
                for (int ct = 0; ct < 8; ct++) oacc[ct][r] *= alpha;
            }
        }

        float pexp[4][4], sum[4];
#pragma unroll
        for (int r = 0; r < 4; r++) sum[r] = 0.0f;
#pragma unroll
        for (int g = 0; g < 4; g++)
#pragma unroll
            for (int r = 0; r < 4; r++) {
                pexp[g][r] = __expf(s[g][r] - m_run[r]);
                sum[r] += pexp[g][r];
            }
#pragma unroll
        for (int off = 8; off >= 1; off >>= 1)
#pragma unroll
            for (int r = 0; r < 4; r++)
                sum[r] += __shfl_xor(sum[r], off);
#pragma unroll
        for (int r = 0; r < 4; r++) l_run[r] += sum[r];

        // ---- P (C-layout) -> wave-local LDS -> A-frags ----
#pragma unroll
        for (int g = 0; g < 4; g++)
#pragma unroll
            for (int r = 0; r < 4; r++)
                sm.s.p[w][l4 * 4 + r][g * 16 + l15] = (bf16)pexp[g][r];

        bf16x8 pf0 = *reinterpret_cast<const bf16x8*>(&sm.s.p[w][l15][l4 * 8]);
        bf16x8 pf1 = *reinterpret_cast<const bf16x8*>(&sm.s.p[w][l15][32 + l4 * 8]);

        // ---- PV: O[q][c], 16 MFMA ----
        __builtin_amdgcn_s_setprio(1);
#pragma unroll
        for (int ct = 0; ct < 8; ct++) {
            bf16x8 vf0 = *reinterpret_cast<const bf16x8*>(
                &sm.s.vt[cur][ct * 16 + l15][l4 * 8]);
            bf16x8 vf1 = *reinterpret_cast<const bf16x8*>(
                &sm.s.vt[cur][ct * 16 + l15][32 + l4 * 8]);
            oacc[ct] = __builtin_amdgcn_mfma_f32_16x16x32_bf16(pf0, vf0, oacc[ct], 0, 0, 0);
            oacc[ct] = __builtin_amdgcn_mfma_f32_16x16x32_bf16(pf1, vf1, oacc[ct], 0, 0, 0);
        }
        __builtin_amdgcn_s_setprio(0);

        if (it + 1 < NT) stage_write(cur ^ 1);   // vmcnt wait lands here, not before compute
        __syncthreads();
    }

    // ---- epilogue: normalize, fused residual, transposed write ----
#pragma unroll
    for (int r = 0; r < 4; r++) {
        const float rl = 1.0f / l_run[r];
#pragma unroll
        for (int ct = 0; ct < 8; ct++)
            sm.o[w * 16 + l4 * 4 + r][ct * 16 + l15] = oacc[ct][r] * rl;
    }
    __syncthreads();

    const size_t xbase = (size_t)batch * CD * NN;
    for (int idx = tid; idx < QBLK * CD; idx += 256) {
        const int c = idx >> 6;
        const int q = idx & 63;
        const size_t g = xbase + (size_t)c * NN + q0 + q;
        out[g] = x[g] + 0.002f * sm.o[q][c];
    }
}

extern "C" void kernel_launch(void* const* d_in, const int* in_sizes, int n_in,
                              void* d_out, int out_size, void* d_ws, size_t ws_size,
                              hipStream_t stream) {
    const float* x = (const float*)d_in[0];
    float* out = (float*)d_out;
    bf16* ft = (bf16*)d_ws;   // 8 MB

    dim3 tb1(32, 8);
    dim3 tg1(NN / 32, CD / 32, BATCH);
    transpose_to_bf16<<<tg1, tb1, 0, stream>>>(x, ft);

    attn_kernel<<<512, 256, 0, stream>>>(x, ft, out);
}